// Round 6
// baseline (136.083 us; speedup 1.0000x reference)
//
#include <hip/hip_runtime.h>
#include <hip/hip_bf16.h>

// Problem constants (setup_inputs): B=2, N=16384, M=1024, IN=OUT=256
#define NPTS    32768
#define K_DIM   256
#define O_DIM   256
#define M_ATOMS 1024

typedef __attribute__((ext_vector_type(8))) short short8;
typedef __attribute__((ext_vector_type(4))) float f32x4;

// RNE split v = hi + lo (both bf16). ~3 VALU/elem: cvt(pk), shl, sub, cvt(pk).
__device__ __forceinline__ void split1(float v, short* h, short* l) {
  unsigned short hu = __bfloat16_as_ushort(__float2bfloat16(v));
  *h = (short)hu;
  float r = v - __uint_as_float((unsigned)hu << 16);
  *l = (short)__bfloat16_as_ushort(__float2bfloat16(r));
}

__device__ __forceinline__ void cvt8(const f32x4 f0, const f32x4 f1,
                                     short8* h, short8* l) {
#pragma unroll
  for (int j = 0; j < 4; ++j) {
    short hh, ll;
    split1(f0[j], &hh, &ll);
    (*h)[j] = hh; (*l)[j] = ll;
    split1(f1[j], &hh, &ll);
    (*h)[j + 4] = hh; (*l)[j + 4] = ll;
  }
}

// async global->LDS, 16B per lane; LDS dest = wave-uniform base + lane*16
__device__ __forceinline__ void async16(void* l, const void* g) {
  __builtin_amdgcn_global_load_lds(
      (const __attribute__((address_space(1))) void*)g,
      (__attribute__((address_space(3))) void*)l, 16, 0, 0);
}

// Kernel 0: W -> bf16 hi/lo in MFMA-fragment-major layout [kc8][ct16][lane64][e8].
// col = ct*16 + (lane&15), k = kc*32 + (lane>>4)*8 + e  (layout verified R1-R4).
__global__ __launch_bounds__(256) void wprep_kernel(const float* __restrict__ W,
                                                    unsigned short* __restrict__ whF,
                                                    unsigned short* __restrict__ wlF) {
  int t = blockIdx.x * 256 + threadIdx.x;   // 0..8191
  int lane = t & 63;
  int ct = (t >> 6) & 15;
  int kc = t >> 10;
  int col = ct * 16 + (lane & 15);
  int k0 = kc * 32 + (lane >> 4) * 8;
  const float* src = W + (size_t)col * K_DIM + k0;
  f32x4 f0 = *(const f32x4*)(src);
  f32x4 f1 = *(const f32x4*)(src + 4);
  short8 h, l;
  cvt8(f0, f1, &h, &l);
  *(short8*)(whF + (size_t)t * 8) = h;
  *(short8*)(wlF + (size_t)t * 8) = l;
}

// Fused GEMM + omega + sin. 512 blocks x 512 threads (8 waves).
// Block b: points [pb, pb+256) (pb=(b>>2)*256), cols [cq*64, cq*64+64) (cq=b&3).
// Wave w: 32 points (2 row-tiles) x 64 cols. W-quarter (hi+lo, 64KB) staged to
// LDS ONCE; main K-loop has ZERO barriers (waves fully independent).
__global__ __launch_bounds__(512, 4) void fused_kernel(
    const float* __restrict__ x, const float* __restrict__ qc,
    const float* __restrict__ atoms,
    const unsigned short* __restrict__ whF, const unsigned short* __restrict__ wlF,
    const float* __restrict__ bias,
    const float* __restrict__ fw1, const float* __restrict__ fb1,
    const float* __restrict__ fw2, const float* __restrict__ fb2,
    float* __restrict__ out) {
  __shared__ char lds[65536];               // W-quarter: hi @0, lo @32768; reused for atoms
  const int lane = threadIdx.x & 63;
  const int w = threadIdx.x >> 6;
  const int lrow = lane & 15;
  const int lk = lane >> 4;
  const int pb = (int)(blockIdx.x >> 2) * 256;
  const int cq = blockIdx.x & 3;
  const int pbase = pb + w * 32;

  // ---- stage W quarter into LDS (once) ----
  // whF layout [kc8][ct16][lane64][e8]; we need ct in [cq*4, cq*4+4) per kc.
  {
    const char* whB = (const char*)whF;
    const char* wlB = (const char*)wlF;
    const int t = threadIdx.x;
    const int inner = (t & 255) * 16;       // wave-uniform + lane*16 (per 4-wave group)
    const int kco = t >> 8;                 // 0 or 1, wave-uniform
#pragma unroll
    for (int p = 0; p < 4; ++p) {
      const int kc = p * 2 + kco;
      async16(lds + kc * 4096 + inner,
              whB + kc * 16384 + cq * 4096 + inner);
      async16(lds + 32768 + kc * 4096 + inner,
              wlB + kc * 16384 + cq * 4096 + inner);
    }
  }

  // bias for this wave's 4 col-tiles
  float bias_r[4];
#pragma unroll
  for (int ct = 0; ct < 4; ++ct) bias_r[ct] = bias[cq * 64 + ct * 16 + lrow];

  // A row pointers (2 row-tiles), at col lk*8
  const float* xr0 = x + (size_t)(pbase + lrow) * K_DIM + lk * 8;
  const float* xr1 = xr0 + 16 * K_DIM;

  // pipeline: preload kc=0
  f32x4 c00 = *(const f32x4*)(xr0);
  f32x4 c01 = *(const f32x4*)(xr0 + 4);
  f32x4 c10 = *(const f32x4*)(xr1);
  f32x4 c11 = *(const f32x4*)(xr1 + 4);

  f32x4 acc[2][4];
#pragma unroll
  for (int t = 0; t < 2; ++t)
#pragma unroll
    for (int ct = 0; ct < 4; ++ct) acc[t][ct] = (f32x4){0.f, 0.f, 0.f, 0.f};

  __syncthreads();                          // W staged; ONLY barrier before GEMM

#pragma unroll 1
  for (int kc = 0; kc < 8; ++kc) {
    f32x4 n00, n01, n10, n11;
    if (kc < 7) {                           // issue next A loads early
      const float* p0 = xr0 + (kc + 1) * 32;
      const float* p1 = xr1 + (kc + 1) * 32;
      n00 = *(const f32x4*)(p0); n01 = *(const f32x4*)(p0 + 4);
      n10 = *(const f32x4*)(p1); n11 = *(const f32x4*)(p1 + 4);
    }
    short8 ahi0, alo0, ahi1, alo1;
    cvt8(c00, c01, &ahi0, &alo0);
    cvt8(c10, c11, &ahi1, &alo1);
    const char* bp = lds + kc * 4096;
#pragma unroll
    for (int ct = 0; ct < 4; ++ct) {
      short8 bh = *(const short8*)(bp + ct * 1024 + lane * 16);
      short8 bl = *(const short8*)(bp + 32768 + ct * 1024 + lane * 16);
      acc[0][ct] = __builtin_amdgcn_mfma_f32_16x16x32_bf16(ahi0, bh, acc[0][ct], 0, 0, 0);
      acc[1][ct] = __builtin_amdgcn_mfma_f32_16x16x32_bf16(ahi1, bh, acc[1][ct], 0, 0, 0);
      acc[0][ct] = __builtin_amdgcn_mfma_f32_16x16x32_bf16(alo0, bh, acc[0][ct], 0, 0, 0);
      acc[1][ct] = __builtin_amdgcn_mfma_f32_16x16x32_bf16(alo1, bh, acc[1][ct], 0, 0, 0);
      acc[0][ct] = __builtin_amdgcn_mfma_f32_16x16x32_bf16(ahi0, bl, acc[0][ct], 0, 0, 0);
      acc[1][ct] = __builtin_amdgcn_mfma_f32_16x16x32_bf16(ahi1, bl, acc[1][ct], 0, 0, 0);
    }
    c00 = n00; c01 = n01; c10 = n10; c11 = n11;
  }

  // ---- omega epilogue: overwrite first 16KB of LDS with atoms ----
  __syncthreads();                          // all waves done reading W
  const int batch = pb >> 14;               // 256 | 16384, no straddle
  const float* A = atoms + (size_t)batch * M_ATOMS * 3;
  f32x4* at4 = (f32x4*)lds;
  {
    int i = threadIdx.x * 2;                // 2 atoms per thread
    const float* ap = A + i * 3;
    float ax = ap[0], ay = ap[1], az = ap[2];
    at4[i] = (f32x4){ax, ay, az, ax * ax + ay * ay + az * az};
    ax = ap[3]; ay = ap[4]; az = ap[5];
    at4[i + 1] = (f32x4){ax, ay, az, ax * ax + ay * ay + az * az};
  }
  __syncthreads();

  // 2 lanes per point: point = lane&31, segment = lane>>5 (512 atoms each)
  const int pt = pbase + (lane & 31);
  const float qx = qc[(size_t)pt * 3 + 0];
  const float qy = qc[(size_t)pt * 3 + 1];
  const float qz = qc[(size_t)pt * 3 + 2];
  float m0 = 3.0e38f, m1 = 3.0e38f, m2 = 3.0e38f, m3 = 3.0e38f;
  const int i0 = (lane >> 5) * 512;
  for (int i = i0; i < i0 + 512; i += 4) {
    f32x4 v0 = at4[i + 0], v1 = at4[i + 1], v2 = at4[i + 2], v3 = at4[i + 3];
    float d;
    d = v0[0] * qx; d = __fmaf_rn(v0[1], qy, d); d = __fmaf_rn(v0[2], qz, d);
    m0 = fminf(m0, __fmaf_rn(d, -2.0f, v0[3]));
    d = v1[0] * qx; d = __fmaf_rn(v1[1], qy, d); d = __fmaf_rn(v1[2], qz, d);
    m1 = fminf(m1, __fmaf_rn(d, -2.0f, v1[3]));
    d = v2[0] * qx; d = __fmaf_rn(v2[1], qy, d); d = __fmaf_rn(v2[2], qz, d);
    m2 = fminf(m2, __fmaf_rn(d, -2.0f, v2[3]));
    d = v3[0] * qx; d = __fmaf_rn(v3[1], qy, d); d = __fmaf_rn(v3[2], qz, d);
    m3 = fminf(m3, __fmaf_rn(d, -2.0f, v3[3]));
  }
  float md = fminf(fminf(m0, m1), fminf(m2, m3));
  md = fminf(md, __shfl_xor(md, 32));       // combine the two atom segments
  md += qx * qx + qy * qy + qz * qz;        // |q-a|^2 = |q|^2 - 2 q.a + |a|^2
  float mind = sqrtf(fmaxf(md, 1.0e-4f));   // sqrt/max monotone -> commute with min

  float facc = fb2[0];
#pragma unroll
  for (int j = 0; j < 16; ++j) {
    float z = fw1[j * 3 + 0] * qx + fw1[j * 3 + 1] * qy + fw1[j * 3 + 2] * qz + fb1[j];
    facc += fw2[j] * log1pf(__expf(z));     // softplus
  }
  float ls = fminf(fmaxf(facc, 0.0f), 5.0f); // fmaxf(NaN,0)=0 == nan_to_num(clip)
  float omega_l = 30.0f * (1.0f + ls * __expf(-mind));

  // row r of tile t needs omega of point t*16 + lk*4 + j (lane index < 32)
  float om[2][4];
#pragma unroll
  for (int t = 0; t < 2; ++t)
#pragma unroll
    for (int j = 0; j < 4; ++j)
      om[t][j] = __shfl(omega_l, t * 16 + lk * 4 + j);

  // ---- store: out[pt, col] = sin(omega * (acc + bias)) ----
#pragma unroll
  for (int t = 0; t < 2; ++t) {
#pragma unroll
    for (int ct = 0; ct < 4; ++ct) {
#pragma unroll
      for (int j = 0; j < 4; ++j) {
        float pre = acc[t][ct][j] + bias_r[ct];
        out[(size_t)(pbase + t * 16 + lk * 4 + j) * O_DIM + cq * 64 + ct * 16 + lrow] =
            __sinf(om[t][j] * pre);
      }
    }
  }
}

extern "C" void kernel_launch(void* const* d_in, const int* in_sizes, int n_in,
                              void* d_out, int out_size, void* d_ws, size_t ws_size,
                              hipStream_t stream) {
  (void)in_sizes; (void)n_in; (void)out_size; (void)ws_size;
  const float* x     = (const float*)d_in[0];
  const float* qc    = (const float*)d_in[1];
  const float* atoms = (const float*)d_in[2];
  const float* W     = (const float*)d_in[3];
  const float* b     = (const float*)d_in[4];
  const float* fw1   = (const float*)d_in[5];
  const float* fb1   = (const float*)d_in[6];
  const float* fw2   = (const float*)d_in[7];
  const float* fb2   = (const float*)d_in[8];
  float* out = (float*)d_out;

  // workspace: whF[65536] u16 (128 KB) | wlF[65536] u16 (128 KB)
  unsigned short* whF = (unsigned short*)d_ws;
  unsigned short* wlF = whF + 65536;

  wprep_kernel<<<32, 256, 0, stream>>>(W, whF, wlF);
  fused_kernel<<<512, 512, 0, stream>>>(x, qc, atoms, whF, wlF, b,
                                        fw1, fb1, fw2, fb2, out);
}